// Round 6
// baseline (92.954 us; speedup 1.0000x reference)
//
#include <hip/hip_runtime.h>
#include <hip/hip_bf16.h>

#define B 2
#define C 64
#define N 4096          // 16*16*16
#define EPS 1e-5f
#define KSEG 16
#define SEGLEN 256      // N / KSEG
// 0.125 * log2(e): fold softmax scale AND exp->exp2 conversion into q
#define QSCALE_LOG2E 0.18033688f

using short8 = __attribute__((ext_vector_type(8))) short;
using f32x16 = __attribute__((ext_vector_type(16))) float;

__device__ inline short f2bf(float f) {
  __hip_bfloat16 h = __float2bfloat16(f);
  union { __hip_bfloat16 h; short s; } u; u.h = h; return u.s;
}
__device__ inline float bf2f(short s) {
  union { unsigned u; float f; } u;
  u.u = ((unsigned)(unsigned short)s) << 16;
  return u.f;
}
// single-instruction pack of two f32 -> bf16x2 (lo=a, hi=b), RNE (T12 recipe)
__device__ inline int cvtpk(float a, float b) {
  int r;
  asm("v_cvt_pk_bf16_f32 %0, %1, %2" : "=v"(r) : "v"(a), "v"(b));
  return r;
}

// ---------------- GroupNorm partial sums ----------------
// grid 512 = 32 (b,g) x 16 slices, 256 thr, 1 float4/thread.
__global__ __launch_bounds__(256) void gn_part_kernel(
    const float* __restrict__ x, float2* __restrict__ part) {
  int blk = blockIdx.x;
  int bg = blk >> 4, sl = blk & 15;
  const float4* xv = (const float4*)(x + (size_t)bg * 4 * N) + sl * 256;
  int tid = threadIdx.x;
  float4 v = xv[tid];
  float s = v.x + v.y + v.z + v.w;
  float s2 = v.x * v.x + v.y * v.y + v.z * v.z + v.w * v.w;
  __shared__ float ss[256], ss2[256];
  ss[tid] = s; ss2[tid] = s2;
  __syncthreads();
  for (int st = 128; st > 0; st >>= 1) {
    if (tid < st) { ss[tid] += ss[tid + st]; ss2[tid] += ss2[tid + st]; }
    __syncthreads();
  }
  if (tid == 0) part[blk] = make_float2(ss[0], ss2[0]);
}

// ---------------- fused gn-finalize + norm + q/k/v conv (8 outputs/block) ---
// q_t,k_t: bf16 [b][pos][ch] (q pre-scaled by 0.125*log2e); v: bf16 [b][ch][pos]
__global__ __launch_bounds__(256) void qkv_kernel(
    const float* __restrict__ x, const float2* __restrict__ part,
    const float* __restrict__ gw, const float* __restrict__ gb,
    const float* __restrict__ qw, const float* __restrict__ qb,
    const float* __restrict__ kw, const float* __restrict__ kb,
    const float* __restrict__ vw, const float* __restrict__ vb,
    short* __restrict__ q_t, short* __restrict__ k_t, short* __restrict__ v_b) {
  int o0 = blockIdx.y * 8, b = blockIdx.z;
  int tid = threadIdx.x;

  // finalize groupnorm stats (redundant per block; part[] is 4KB L2-hot)
  __shared__ float asl[C], bsl[C];
  if (tid < C) {
    int c = tid, g = c >> 2;
    int bg = b * 16 + g;
    float s = 0.f, s2 = 0.f;
#pragma unroll
    for (int sl = 0; sl < 16; ++sl) {
      float2 p = part[bg * 16 + sl];
      s += p.x; s2 += p.y;
    }
    float mean = s * (1.f / 16384.f);
    float var = s2 * (1.f / 16384.f) - mean * mean;
    float inv = rsqrtf(var + EPS);
    float a = inv * gw[c];
    asl[c] = a;
    bsl[c] = gb[c] - mean * a;
  }
  __syncthreads();

  int pos = blockIdx.x * 256 + tid;
  const float* xp = x + (size_t)b * C * N + pos;

  float sq[8], sk[8], sv[8];
#pragma unroll
  for (int j = 0; j < 8; ++j) { sq[j] = 0.f; sk[j] = 0.f; sv[j] = 0.f; }
#pragma unroll
  for (int c = 0; c < C; ++c) {
    float hv = fmaf(xp[(size_t)c * N], asl[c], bsl[c]);
#pragma unroll
    for (int j = 0; j < 8; ++j) {
      sq[j] = fmaf(qw[(o0 + j) * C + c], hv, sq[j]);
      sk[j] = fmaf(kw[(o0 + j) * C + c], hv, sk[j]);
      sv[j] = fmaf(vw[(o0 + j) * C + c], hv, sv[j]);
    }
  }
  size_t ti = ((size_t)b * N + pos) * C;
  short8 qv, kv;
#pragma unroll
  for (int j = 0; j < 8; ++j) {
    qv[j] = f2bf((sq[j] + qb[o0 + j]) * QSCALE_LOG2E);
    kv[j] = f2bf(sk[j] + kb[o0 + j]);
  }
  *(short8*)&q_t[ti + o0] = qv;
  *(short8*)&k_t[ti + o0] = kv;
#pragma unroll
  for (int j = 0; j < 8; ++j)
    v_b[((size_t)b * C + o0 + j) * N + pos] = f2bf(sv[j] + vb[o0 + j]);
}

// softmax (exp2 domain, no max) + pack P into two PV B-fragments via cvt_pk
__device__ inline void softpack(f32x16& s, int hi, float& lsum,
                                short8& p0, short8& p1) {
  float ps = 0.f;
#pragma unroll
  for (int i = 0; i < 16; ++i) { s[i] = exp2f(s[i]); ps += s[i]; }
  lsum += ps;   // cross-pair shfl deferred to epilogue (linear)
  union U { int i[4]; short8 v; } f0, f1;
  {
    int x0 = cvtpk(s[0], s[1]), z0 = cvtpk(s[2], s[3]);
    int y0 = cvtpk(s[4], s[5]), w0 = cvtpk(s[6], s[7]);
    int xs = __shfl_xor(x0, 32), zs = __shfl_xor(z0, 32);
    int ys = __shfl_xor(y0, 32), ws2 = __shfl_xor(w0, 32);
    f0.i[0] = hi ? ys : x0; f0.i[1] = hi ? ws2 : z0;
    f0.i[2] = hi ? y0 : xs; f0.i[3] = hi ? w0 : zs;
  }
  {
    int x0 = cvtpk(s[8], s[9]), z0 = cvtpk(s[10], s[11]);
    int y0 = cvtpk(s[12], s[13]), w0 = cvtpk(s[14], s[15]);
    int xs = __shfl_xor(x0, 32), zs = __shfl_xor(z0, 32);
    int ys = __shfl_xor(y0, 32), ws2 = __shfl_xor(w0, 32);
    f1.i[0] = hi ? ys : x0; f1.i[1] = hi ? ws2 : z0;
    f1.i[2] = hi ? y0 : xs; f1.i[3] = hi ? w0 : zs;
  }
  p0 = f0.v; p1 = f1.v;
}

// ---------------- MFMA flash attention (single-buffer, R4 structure) -------
// grid (N/256, KSEG, B), block 256 = 4 independent waves, 64 queries each.
__global__ __launch_bounds__(256, 2) void attn_kernel(
    const short* __restrict__ q_t, const short* __restrict__ k_t,
    const short* __restrict__ v_b, short* __restrict__ opart,
    float* __restrict__ lpart) {
  int b = blockIdx.z, s = blockIdx.y;
  int l = threadIdx.x & 63;
  int q0 = blockIdx.x * 256 + (threadIdx.x >> 6) * 64;
  int lo5 = l & 31;
  int hi = l >> 5;

  const short* qp = q_t + (size_t)b * N * C;
  const short* kp = k_t + (size_t)b * N * C;
  const short* vp = v_b + (size_t)b * C * N;

  short8 qf[2][4];
#pragma unroll
  for (int qt = 0; qt < 2; ++qt)
#pragma unroll
    for (int t = 0; t < 4; ++t)
      qf[qt][t] = *(const short8*)&qp[(size_t)(q0 + qt * 32 + lo5) * C + t * 16 + hi * 8];

  f32x16 oacc00, oacc01, oacc10, oacc11;   // [qt][c-half]
#pragma unroll
  for (int i = 0; i < 16; ++i) { oacc00[i] = 0.f; oacc01[i] = 0.f; oacc10[i] = 0.f; oacc11[i] = 0.f; }
  float lsum[2] = {0.f, 0.f};

  int kbase = s * SEGLEN;
  for (int kc = 0; kc < SEGLEN; kc += 32) {
    int k0 = kbase + kc;
    short8 kf[4];
#pragma unroll
    for (int t = 0; t < 4; ++t)
      kf[t] = *(const short8*)&kp[(size_t)(k0 + lo5) * C + t * 16 + hi * 8];
    short8 vf[4];
    vf[0] = *(const short8*)&vp[(size_t)(lo5) * N + k0 + hi * 8];
    vf[1] = *(const short8*)&vp[(size_t)(32 + lo5) * N + k0 + hi * 8];
    vf[2] = *(const short8*)&vp[(size_t)(lo5) * N + k0 + 16 + hi * 8];
    vf[3] = *(const short8*)&vp[(size_t)(32 + lo5) * N + k0 + 16 + hi * 8];

    f32x16 sacc[2];
#pragma unroll
    for (int i = 0; i < 16; ++i) { sacc[0][i] = 0.f; sacc[1][i] = 0.f; }
    __builtin_amdgcn_s_setprio(1);
#pragma unroll
    for (int t = 0; t < 4; ++t) {
      sacc[0] = __builtin_amdgcn_mfma_f32_32x32x16_bf16(kf[t], qf[0][t], sacc[0], 0, 0, 0);
      sacc[1] = __builtin_amdgcn_mfma_f32_32x32x16_bf16(kf[t], qf[1][t], sacc[1], 0, 0, 0);
    }
    __builtin_amdgcn_s_setprio(0);

    short8 pf00, pf01, pf10, pf11;
    softpack(sacc[0], hi, lsum[0], pf00, pf01);
    softpack(sacc[1], hi, lsum[1], pf10, pf11);

    __builtin_amdgcn_s_setprio(1);
    oacc00 = __builtin_amdgcn_mfma_f32_32x32x16_bf16(vf[0], pf00, oacc00, 0, 0, 0);
    oacc01 = __builtin_amdgcn_mfma_f32_32x32x16_bf16(vf[1], pf00, oacc01, 0, 0, 0);
    oacc10 = __builtin_amdgcn_mfma_f32_32x32x16_bf16(vf[0], pf10, oacc10, 0, 0, 0);
    oacc11 = __builtin_amdgcn_mfma_f32_32x32x16_bf16(vf[1], pf10, oacc11, 0, 0, 0);
    oacc00 = __builtin_amdgcn_mfma_f32_32x32x16_bf16(vf[2], pf01, oacc00, 0, 0, 0);
    oacc01 = __builtin_amdgcn_mfma_f32_32x32x16_bf16(vf[3], pf01, oacc01, 0, 0, 0);
    oacc10 = __builtin_amdgcn_mfma_f32_32x32x16_bf16(vf[2], pf11, oacc10, 0, 0, 0);
    oacc11 = __builtin_amdgcn_mfma_f32_32x32x16_bf16(vf[3], pf11, oacc11, 0, 0, 0);
    __builtin_amdgcn_s_setprio(0);
  }

#pragma unroll
  for (int qt = 0; qt < 2; ++qt) {
    lsum[qt] += __shfl_xor(lsum[qt], 32);
    int qq = q0 + qt * 32 + lo5;
    short* op = opart + (size_t)(b * KSEG + s) * C * N;
#pragma unroll
    for (int r = 0; r < 16; ++r) {
      int c = (r & 3) + 8 * (r >> 2) + 4 * hi;
      float v0 = (qt == 0) ? oacc00[r] : oacc10[r];
      float v1 = (qt == 0) ? oacc01[r] : oacc11[r];
      op[(size_t)c * N + qq] = f2bf(v0);
      op[(size_t)(c + 32) * N + qq] = f2bf(v1);
    }
    if (hi == 0) lpart[(size_t)(b * KSEG + s) * N + qq] = lsum[qt];
  }
}

// ---------------- fused merge + proj conv + residual ----------------
// grid (N/64, 2, B), block 256 = 64 pos x 4 waves; each wave owns 8 outputs
// (wave-uniform o-range -> proj weights stay scalar-loaded).
__global__ __launch_bounds__(256) void mergeproj_kernel(
    const short* __restrict__ opart, const float* __restrict__ lpart,
    const float* __restrict__ pw, const float* __restrict__ pb,
    const float* __restrict__ x, float* __restrict__ out) {
  int b = blockIdx.z;
  int pos = blockIdx.x * 64 + (threadIdx.x & 63);
  int o0 = blockIdx.y * 32 + (threadIdx.x >> 6) * 8;

  // total attention weight for this query position
  float L = 0.f;
#pragma unroll
  for (int s = 0; s < KSEG; ++s) L += lpart[(size_t)(b * KSEG + s) * N + pos];
  float invL = 1.f / L;

  float acc[8];
#pragma unroll
  for (int j = 0; j < 8; ++j) acc[j] = 0.f;

  const short* opb = opart + (size_t)b * KSEG * C * N + pos;
#pragma unroll
  for (int c = 0; c < C; ++c) {
    float a = 0.f;
#pragma unroll
    for (int s = 0; s < KSEG; ++s)
      a += bf2f(opb[((size_t)s * C + c) * N]);
    a *= invL;
#pragma unroll
    for (int j = 0; j < 8; ++j)
      acc[j] = fmaf(pw[(o0 + j) * C + c], a, acc[j]);
  }
#pragma unroll
  for (int j = 0; j < 8; ++j) {
    size_t oi = (size_t)(b * C + o0 + j) * N + pos;
    out[oi] = x[oi] + acc[j] + pb[o0 + j];
  }
}

extern "C" void kernel_launch(void* const* d_in, const int* in_sizes, int n_in,
                              void* d_out, int out_size, void* d_ws, size_t ws_size,
                              hipStream_t stream) {
  const float* x      = (const float*)d_in[0];
  const float* norm_w = (const float*)d_in[1];
  const float* norm_b = (const float*)d_in[2];
  const float* q_w    = (const float*)d_in[3];
  const float* q_b    = (const float*)d_in[4];
  const float* k_w    = (const float*)d_in[5];
  const float* k_b    = (const float*)d_in[6];
  const float* v_w    = (const float*)d_in[7];
  const float* v_b    = (const float*)d_in[8];
  const float* proj_w = (const float*)d_in[9];
  const float* proj_b = (const float*)d_in[10];
  float* out = (float*)d_out;

  const size_t BCN = (size_t)B * C * N;   // 524288
  // ws layout: q,k,v bf16 (3*BCN*2B) + part (512*8B) + lpart (KSEG*B*N*4B)
  //          + opart bf16 (KSEG*BCN*2B)  => ~30 MB total, ws is ~268 MB
  short* q_t   = (short*)d_ws;
  short* k_t   = q_t + BCN;
  short* vbuf  = k_t + BCN;
  float2* part = (float2*)(vbuf + BCN);
  float* lpart = (float*)(part + 512);
  short* opart = (short*)(lpart + (size_t)KSEG * B * N);

  gn_part_kernel<<<512, 256, 0, stream>>>(x, part);

  qkv_kernel<<<dim3(N / 256, C / 8, B), 256, 0, stream>>>(
      x, part, norm_w, norm_b, q_w, q_b, k_w, k_b, v_w, v_b, q_t, k_t, vbuf);

  attn_kernel<<<dim3(N / 256, KSEG, B), 256, 0, stream>>>(
      q_t, k_t, vbuf, opart, lpart);

  mergeproj_kernel<<<dim3(N / 64, 2, B), 256, 0, stream>>>(
      opart, lpart, proj_w, proj_b, x, out);
}